// Round 8
// baseline (68.770 us; speedup 1.0000x reference)
//
#include <hip/hip_runtime.h>
#include <math.h>
#include <limits.h>

#define HH 128
#define WW 128
#define HW (HH*WW)
#define BB 2
#define CC 14
#define NPAIR 26   // B * (C-1)
#define RPB 8                      // rows per k_C block (1024-thread blocks)
#define NBLK (NPAIR * (HH / RPB))  // 416 k_C blocks (r3 structure: >=2 blocks/CU)

typedef unsigned long long u64;

// ---------------------------------------------------------------------------
// ws layout (bytes):
//   Scol : [BB][CC][WW][16] u8 @ 0       (57344)  column bitmask bytes of the
//          student class-c argmax mask: byte g = rows 8g..8g+7 (bit r = row 8g+r)
//   Tcol : same for teacher      @ 57344  (57344)
//   Hcol : same for (Ls[c]>0.5)  @ 114688 (57344)
//   partials : [NBLK] f32        @ 172032 (1664)  per-block loss partial sums
//
// Measured laws (r0-r7): (1) in-kernel cross-block reduction (fence/ticket or
// scoped atomics) costs MORE than a separate k_fin launch — twice confirmed
// (k_fin+gap ~4.4us, tail ~19ns/block serialized); (2) >=2 co-resident
// blocks/CU required to hide k_C's naked load/barrier latency (r4); (3)
// instruction count barely matters — sync/launch structure does (r0==r1,
// r2==r3 after tail arithmetic). This round: k_C preamble barrier COLLAPSED —
// every thread rebuilds its column masks in registers (7x16B L2 loads,
// redundant but free per law 3), deleting barrier #1 + the mask LDS arrays.
// ---------------------------------------------------------------------------

// distance from row i to nearest set bit in 128-bit mask {lo,hi}; 255 if empty.
// i is wave-uniform in k_C -> uniform branches.
__device__ inline int nbd(u64 lo, u64 hi, int i) {
    int up = 255, down = 255;
    u64 slo, shi;
    if (i == 0)      { slo = lo; shi = hi; }
    else if (i < 64) { slo = (lo >> i) | (hi << (64 - i)); shi = hi >> i; }
    else             { slo = hi >> (i - 64); shi = 0ULL; }
    if (slo)      up = __builtin_ctzll(slo);
    else if (shi) up = 64 + __builtin_ctzll(shi);
    int s = 127 - i;
    u64 llo, lhi;
    if (s == 0)      { llo = lo; lhi = hi; }
    else if (s < 64) { lhi = (hi << s) | (lo >> (64 - s)); llo = lo << s; }
    else             { lhi = lo << (s - 64); llo = 0ULL; }
    if (lhi)      down = __builtin_clzll(lhi);
    else if (llo) down = 64 + __builtin_clzll(llo);
    return min(up, down);
}

__device__ inline ulonglong2 ld16z(const unsigned char* p, size_t off, bool ok) {
    return ok ? *(const ulonglong2*)(p + off) : make_ulonglong2(0ULL, 0ULL);
}

// Split pack: 128 blocks. Blocks 0..63 = student (argmax + hbits -> Scol,Hcol),
// blocks 64..127 = teacher (argmax -> Tcol). Each block = 8 rows x 64 cols of
// one image, 2 px/thread via float2; 13 loads/thread.
__global__ __launch_bounds__(256) void k_pack(
        const float* __restrict__ Ls, const float* __restrict__ Lt,
        unsigned char* __restrict__ Scol, unsigned char* __restrict__ Tcol,
        unsigned char* __restrict__ Hcol) {
    int tid = threadIdx.x;
    int blk = blockIdx.x;
    int st  = blk >> 6;               // 0 = student(+H), 1 = teacher
    int blk2 = blk & 63;
    int b = blk2 >> 5;                // image
    int g = (blk2 >> 1) & 15;         // 8-row group
    int h = blk2 & 1;                 // 64-col half
    int r = tid >> 5;                 // local row 0..7
    int q = tid & 31;                 // col-pair 0..31
    int row = g * 8 + r;
    int col0 = h * 64 + q * 2;
    int jl = q * 2;

    __shared__ unsigned char  labL[8][64];
    __shared__ unsigned short hL[8][64];

    int jc = tid & 63;                // pack-phase column within half
    int cl = tid >> 6;                // class lane 0..3 -> classes 1+cl, +4, ...
    int n0 = b * CC;
    int jj = h * 64 + jc;

    if (st == 0) {                    // ---- student + H ----
        const float2* ps = (const float2*)(Ls + (size_t)b * CC * HW)
                         + ((row * WW + col0) >> 1);
        float2 mS = ps[0];
        int iS0 = 0, iS1 = 0;
        unsigned int hm0 = 0, hm1 = 0;
#pragma unroll
        for (int c = 1; c < CC; ++c) {
            float2 v = ps[(size_t)c * (HW / 2)];
            if (v.x > mS.x) { mS.x = v.x; iS0 = c; }   // first-max tie rule
            if (v.y > mS.y) { mS.y = v.y; iS1 = c; }
            if (v.x > 0.5f) hm0 |= 1u << (c - 1);
            if (v.y > 0.5f) hm1 |= 1u << (c - 1);
        }
        labL[r][jl]     = (unsigned char)iS0;
        labL[r][jl + 1] = (unsigned char)iS1;
        hL[r][jl]     = (unsigned short)hm0;
        hL[r][jl + 1] = (unsigned short)hm1;
        __syncthreads();

        unsigned char  lr[8];
        unsigned short hr[8];
#pragma unroll
        for (int rr = 0; rr < 8; ++rr) { lr[rr] = labL[rr][jc]; hr[rr] = hL[rr][jc]; }
        for (int cc = 1 + cl; cc < CC; cc += 4) {
            unsigned int sb = 0, hbb = 0;
#pragma unroll
            for (int rr = 0; rr < 8; ++rr) {
                sb  |= (unsigned int)(lr[rr] == cc) << rr;
                hbb |= ((unsigned int)(hr[rr] >> (cc - 1)) & 1u) << rr;
            }
            size_t off = ((size_t)(((n0 + cc) << 7) | jj) << 4) + g;
            Scol[off] = (unsigned char)sb;
            Hcol[off] = (unsigned char)hbb;
        }
    } else {                          // ---- teacher ----
        const float2* pt = (const float2*)(Lt + (size_t)b * CC * HW)
                         + ((row * WW + col0) >> 1);
        float2 mT = pt[0];
        int iT0 = 0, iT1 = 0;
#pragma unroll
        for (int c = 1; c < CC; ++c) {
            float2 u = pt[(size_t)c * (HW / 2)];
            if (u.x > mT.x) { mT.x = u.x; iT0 = c; }
            if (u.y > mT.y) { mT.y = u.y; iT1 = c; }
        }
        labL[r][jl]     = (unsigned char)iT0;
        labL[r][jl + 1] = (unsigned char)iT1;
        __syncthreads();

        unsigned char lr[8];
#pragma unroll
        for (int rr = 0; rr < 8; ++rr) lr[rr] = labL[rr][jc];
        for (int cc = 1 + cl; cc < CC; cc += 4) {
            unsigned int tb = 0;
#pragma unroll
            for (int rr = 0; rr < 8; ++rr)
                tb |= (unsigned int)(lr[rr] == cc) << rr;
            size_t off = ((size_t)(((n0 + cc) << 7) | jj) << 4) + g;
            Tcol[off] = (unsigned char)tb;
        }
    }
}

// One block per (pair, 8-row tile), 1024 threads, 2 blocks/CU via
// __launch_bounds__(1024, 8). SINGLE-BARRIER structure: every thread builds
// its own column's fp/es/et masks in registers (7 independent 16B L2-hot
// loads + ~40 bit-ops, redundant across waves — measured-free), then
// column EDT -> sq publish + sfl ballots under ONE barrier -> expanding-ring
// row EDT -> block reduction -> plain store to private partial slot.
__global__ __launch_bounds__(1024, 8) void k_C(
        const unsigned char* __restrict__ Scol, const unsigned char* __restrict__ Tcol,
        const unsigned char* __restrict__ Hcol, const float* __restrict__ Ls,
        float* __restrict__ partials) {
    int n = blockIdx.x >> 4;          // pair (16 row-tiles per pair)
    int t = blockIdx.x & 15;          // row tile
    int tid = threadIdx.x;
    int k = tid >> 7;                 // row r within tile
    int j = tid & (WW - 1);
    int b = n / (CC - 1), c = 1 + (n - b * (CC - 1));
    const float* Lp = Ls + (size_t)(b * CC + c) * HW;

    int i = t * RPB + k;              // this thread's output row
    float lv = Lp[i * WW + j];        // hoisted, coalesced

    // in-register mask build for column j (all threads, no barrier)
    size_t cbase = ((size_t)(((b * CC + c) << 7) | j)) << 4;
    ulonglong2 S  = *(const ulonglong2*)(Scol + cbase);
    ulonglong2 Sl = ld16z(Scol, cbase - 16, j > 0);
    ulonglong2 Sr = ld16z(Scol, cbase + 16, j < WW - 1);
    ulonglong2 Hc = *(const ulonglong2*)(Hcol + cbase);
    // erosion: m & up & down & left & right; shifts insert 0 (border erodes)
    u64 ms0 = S.x, ms1 = S.y;
    u64 U0 = ms0 << 1, U1 = (ms1 << 1) | (ms0 >> 63);
    u64 D0 = (ms0 >> 1) | (ms1 << 63), D1 = ms1 >> 1;
    u64 er0 = ms0 & U0 & D0 & Sl.x & Sr.x;
    u64 er1 = ms1 & U1 & D1 & Sl.y & Sr.y;
    u64 es0 = ms0 & ~er0, es1 = ms1 & ~er1;
    u64 fp0 = es0 & Hc.x, fp1 = es1 & Hc.y;       // pred = es*logit > 0.5

    ulonglong2 T  = *(const ulonglong2*)(Tcol + cbase);
    ulonglong2 Tl = ld16z(Tcol, cbase - 16, j > 0);
    ulonglong2 Tr = ld16z(Tcol, cbase + 16, j < WW - 1);
    u64 mt0 = T.x, mt1 = T.y;
    u64 Ut0 = mt0 << 1, Ut1 = (mt1 << 1) | (mt0 >> 63);
    u64 Dt0 = (mt0 >> 1) | (mt1 << 63), Dt1 = mt1 >> 1;
    u64 ert0 = mt0 & Ut0 & Dt0 & Tl.x & Tr.x;
    u64 ert1 = mt1 & Ut1 & Dt1 & Tl.y & Tr.y;
    u64 et0 = mt0 & ~ert0, et1 = mt1 & ~ert1;

    __shared__ int sfl[2];
    __shared__ uchar4 sq[RPB][WW];    // d1 per map (255 sentinel; squared on read)

    // flags: waves 0-1 (k==0) span all 128 columns; published under sq barrier
    if (tid < 128) {
        u64 bFgP = __ballot((fp0 | fp1) != 0ull);
        u64 bBgP = __ballot((fp0 & fp1) != ~0ull);
        u64 bFgT = __ballot((et0 | et1) != 0ull);
        u64 bBgT = __ballot((et0 & et1) != ~0ull);
        if ((tid & 63) == 0)
            sfl[tid >> 6] = (bFgP ? 1 : 0) | (bBgP ? 2 : 0)
                          | (bFgT ? 4 : 0) | (bBgT ? 8 : 0);
    }

    // column EDT from registers
    int dP  = nbd(fp0, fp1, i);
    int dPb = nbd(~fp0, ~fp1, i);
    int dT  = nbd(et0, et1, i);
    int dTb = nbd(~et0, ~et1, i);

    sq[k][j] = make_uchar4((unsigned char)dP, (unsigned char)dPb,
                           (unsigned char)dT, (unsigned char)dTb);
    __syncthreads();                  // ONE barrier publishes sq + sfl

    int f = sfl[0] | sfl[1];
    bool aP = (f & 3) == 3, aT = (f & 12) == 12;

    int bP = dP * dP, bPb = dPb * dPb, bT = dT * dT, bTb = dTb * dTb;
    int need = 0;
    if (aP) need = max(bP, bPb);
    if (aT) need = max(need, max(bT, bTb));
    // expanding ring: candidates at radius rad are >= rad^2, so once
    // rad^2 >= need (best over maps actually used), the min is final.
    for (int rad = 1; rad < WW; ++rad) {
        int rr = rad * rad;
        if (rr >= need) break;
        if (j >= rad) {
            uchar4 s = sq[k][j - rad];
            bP  = min(bP,  (int)s.x * s.x + rr); bPb = min(bPb, (int)s.y * s.y + rr);
            bT  = min(bT,  (int)s.z * s.z + rr); bTb = min(bTb, (int)s.w * s.w + rr);
        }
        if (j + rad < WW) {
            uchar4 s = sq[k][j + rad];
            bP  = min(bP,  (int)s.x * s.x + rr); bPb = min(bPb, (int)s.y * s.y + rr);
            bT  = min(bT,  (int)s.z * s.z + rr); bTb = min(bTb, (int)s.w * s.w + rr);
        }
        need = 0;
        if (aP) need = max(bP, bPb);
        if (aT) need = max(need, max(bT, bTb));
    }

    float fieldP = aP ? (float)(bP + bPb) : 0.0f;
    float fieldT = aT ? (float)(bT + bTb) : 0.0f;

    bool es = ((i < 64 ? (es0 >> i) : (es1 >> (i - 64))) & 1ull) != 0;
    bool et = ((i < 64 ? (et0 >> i) : (et1 >> (i - 64))) & 1ull) != 0;
    float predv = es ? lv : 0.0f;
    float targv = et ? (float)c : 0.0f;
    float diff = predv - targv;
    float v = diff * diff * (fieldP + fieldT);

    for (int o = 32; o > 0; o >>= 1) v += __shfl_down(v, o);
    __shared__ float wsum[16];
    int lane = tid & 63, w = tid >> 6;
    if (lane == 0) wsum[w] = v;
    __syncthreads();
    if (tid == 0) {
        float tot = 0.0f;
#pragma unroll
        for (int q = 0; q < 16; ++q) tot += wsum[q];
        partials[blockIdx.x] = tot;   // private slot: no atomic, no fence
    }
}

// final reduction: 416 partials -> 26 pair losses -> scalar. One 64-thread
// block; kernel boundary guarantees k_C's stores are visible.
__global__ void k_fin(const float* __restrict__ partials, float* __restrict__ out) {
    int tid = threadIdx.x;            // 0..63
    float vv = 0.0f;
    if (tid < NPAIR) {
        float s = 0.0f;
#pragma unroll
        for (int t = 0; t < 16; ++t) s += partials[tid * 16 + t];
        vv = logf(s * (1.0f / (float)HW) + 1.0f);
    }
    for (int o = 32; o > 0; o >>= 1) vv += __shfl_down(vv, o);
    if (tid == 0) out[0] = 0.5f * vv; // (1 - LOSS_WEIGHT) * sum
}

extern "C" void kernel_launch(void* const* d_in, const int* in_sizes, int n_in,
                              void* d_out, int out_size, void* d_ws, size_t ws_size,
                              hipStream_t stream) {
    const float* Ls = (const float*)d_in[0];
    const float* Lt = (const float*)d_in[1];
    float* out = (float*)d_out;

    char* w = (char*)d_ws;
    unsigned char* Sc   = (unsigned char*)(w);
    unsigned char* Tc   = (unsigned char*)(w + 57344);
    unsigned char* Hc   = (unsigned char*)(w + 114688);
    float*         part = (float*)        (w + 172032);

    k_pack<<<128, 256, 0, stream>>>(Ls, Lt, Sc, Tc, Hc);
    k_C<<<NBLK, 1024, 0, stream>>>(Sc, Tc, Hc, Ls, part);
    k_fin<<<1, 64, 0, stream>>>(part, out);
}

// Round 9
// 67.058 us; speedup vs baseline: 1.0255x; 1.0255x over previous
//
#include <hip/hip_runtime.h>
#include <math.h>
#include <limits.h>

#define HH 128
#define WW 128
#define HW (HH*WW)
#define BB 2
#define CC 14
#define NPAIR 26   // B * (C-1)
#define RPB 8                      // rows per k_C block (1024-thread blocks)
#define NBLK (NPAIR * (HH / RPB))  // 416 k_C blocks (r3 structure: >=2 blocks/CU)

typedef unsigned long long u64;

// ---------------------------------------------------------------------------
// ws layout (bytes):
//   Scol : [BB][CC][WW][16] u8 @ 0       (57344)  column bitmask bytes of the
//          student class-c argmax mask: byte g = rows 8g..8g+7 (bit r = row 8g+r)
//   Tcol : same for teacher      @ 57344  (57344)
//   Hcol : same for (Ls[c]>0.5)  @ 114688 (57344)
//   partials : [NBLK] f32        @ 172032 (1664)  per-block loss partial sums
//
// Measured laws (r0-r8):
// (1) in-kernel cross-block reduction (fence/ticket or scoped atomics) costs
//     MORE than a separate k_fin launch — twice confirmed (~19ns/block tail);
// (2) >=2 co-resident blocks/CU required to hide k_C's load/barrier latency;
// (3) instruction count barely matters, but L2 TRAFFIC does: the r8
//     all-thread redundant mask build (48MB vs 7MB L2 traffic) cost +1.26us —
//     role-split preamble (this version) is the optimum;
// (4) k_pack widening pays ~linearly until 128 blocks.
// This is the r7 champion configuration (67.51us), restored.
// ---------------------------------------------------------------------------

// distance from row i to nearest set bit in 128-bit mask {lo,hi}; 255 if empty.
// i is wave-uniform in k_C -> uniform branches.
__device__ inline int nbd(u64 lo, u64 hi, int i) {
    int up = 255, down = 255;
    u64 slo, shi;
    if (i == 0)      { slo = lo; shi = hi; }
    else if (i < 64) { slo = (lo >> i) | (hi << (64 - i)); shi = hi >> i; }
    else             { slo = hi >> (i - 64); shi = 0ULL; }
    if (slo)      up = __builtin_ctzll(slo);
    else if (shi) up = 64 + __builtin_ctzll(shi);
    int s = 127 - i;
    u64 llo, lhi;
    if (s == 0)      { llo = lo; lhi = hi; }
    else if (s < 64) { lhi = (hi << s) | (lo >> (64 - s)); llo = lo << s; }
    else             { lhi = lo << (s - 64); llo = 0ULL; }
    if (lhi)      down = __builtin_clzll(lhi);
    else if (llo) down = 64 + __builtin_clzll(llo);
    return min(up, down);
}

__device__ inline ulonglong2 ld16z(const unsigned char* p, size_t off, bool ok) {
    return ok ? *(const ulonglong2*)(p + off) : make_ulonglong2(0ULL, 0ULL);
}

// Split pack: 128 blocks. Blocks 0..63 = student (argmax + hbits -> Scol,Hcol),
// blocks 64..127 = teacher (argmax -> Tcol). Each block = 8 rows x 64 cols of
// one image, 2 px/thread via float2; 13 loads/thread (halved vs r6).
__global__ __launch_bounds__(256) void k_pack(
        const float* __restrict__ Ls, const float* __restrict__ Lt,
        unsigned char* __restrict__ Scol, unsigned char* __restrict__ Tcol,
        unsigned char* __restrict__ Hcol) {
    int tid = threadIdx.x;
    int blk = blockIdx.x;
    int st  = blk >> 6;               // 0 = student(+H), 1 = teacher
    int blk2 = blk & 63;
    int b = blk2 >> 5;                // image
    int g = (blk2 >> 1) & 15;         // 8-row group
    int h = blk2 & 1;                 // 64-col half
    int r = tid >> 5;                 // local row 0..7
    int q = tid & 31;                 // col-pair 0..31
    int row = g * 8 + r;
    int col0 = h * 64 + q * 2;
    int jl = q * 2;

    __shared__ unsigned char  labL[8][64];
    __shared__ unsigned short hL[8][64];

    int jc = tid & 63;                // pack-phase column within half
    int cl = tid >> 6;                // class lane 0..3 -> classes 1+cl, +4, ...
    int n0 = b * CC;
    int jj = h * 64 + jc;

    if (st == 0) {                    // ---- student + H ----
        const float2* ps = (const float2*)(Ls + (size_t)b * CC * HW)
                         + ((row * WW + col0) >> 1);
        float2 mS = ps[0];
        int iS0 = 0, iS1 = 0;
        unsigned int hm0 = 0, hm1 = 0;
#pragma unroll
        for (int c = 1; c < CC; ++c) {
            float2 v = ps[(size_t)c * (HW / 2)];
            if (v.x > mS.x) { mS.x = v.x; iS0 = c; }   // first-max tie rule
            if (v.y > mS.y) { mS.y = v.y; iS1 = c; }
            if (v.x > 0.5f) hm0 |= 1u << (c - 1);
            if (v.y > 0.5f) hm1 |= 1u << (c - 1);
        }
        labL[r][jl]     = (unsigned char)iS0;
        labL[r][jl + 1] = (unsigned char)iS1;
        hL[r][jl]     = (unsigned short)hm0;
        hL[r][jl + 1] = (unsigned short)hm1;
        __syncthreads();

        unsigned char  lr[8];
        unsigned short hr[8];
#pragma unroll
        for (int rr = 0; rr < 8; ++rr) { lr[rr] = labL[rr][jc]; hr[rr] = hL[rr][jc]; }
        for (int cc = 1 + cl; cc < CC; cc += 4) {
            unsigned int sb = 0, hbb = 0;
#pragma unroll
            for (int rr = 0; rr < 8; ++rr) {
                sb  |= (unsigned int)(lr[rr] == cc) << rr;
                hbb |= ((unsigned int)(hr[rr] >> (cc - 1)) & 1u) << rr;
            }
            size_t off = ((size_t)(((n0 + cc) << 7) | jj) << 4) + g;
            Scol[off] = (unsigned char)sb;
            Hcol[off] = (unsigned char)hbb;
        }
    } else {                          // ---- teacher ----
        const float2* pt = (const float2*)(Lt + (size_t)b * CC * HW)
                         + ((row * WW + col0) >> 1);
        float2 mT = pt[0];
        int iT0 = 0, iT1 = 0;
#pragma unroll
        for (int c = 1; c < CC; ++c) {
            float2 u = pt[(size_t)c * (HW / 2)];
            if (u.x > mT.x) { mT.x = u.x; iT0 = c; }
            if (u.y > mT.y) { mT.y = u.y; iT1 = c; }
        }
        labL[r][jl]     = (unsigned char)iT0;
        labL[r][jl + 1] = (unsigned char)iT1;
        __syncthreads();

        unsigned char lr[8];
#pragma unroll
        for (int rr = 0; rr < 8; ++rr) lr[rr] = labL[rr][jc];
        for (int cc = 1 + cl; cc < CC; cc += 4) {
            unsigned int tb = 0;
#pragma unroll
            for (int rr = 0; rr < 8; ++rr)
                tb |= (unsigned int)(lr[rr] == cc) << rr;
            size_t off = ((size_t)(((n0 + cc) << 7) | jj) << 4) + g;
            Tcol[off] = (unsigned char)tb;
        }
    }
}

// One block per (pair, 8-row tile), 1024 threads (r3 structure, proven best).
// __launch_bounds__(1024, 8): 8 waves/EU = 32 waves/CU = 2 co-resident
// blocks/CU (caps VGPR at 64) — cross-block latency hiding (r4 lesson).
//   preamble (1 barrier): waves 0-1 build student es/fp masks, waves 2-3 build
//   teacher et masks; neighbor columns loaded straight from global (L2).
//   phase 3: column EDT (bit-trick) -> row EDT (early-exit expanding ring)
//            -> block reduction -> plain store to private partial slot.
__global__ __launch_bounds__(1024, 8) void k_C(
        const unsigned char* __restrict__ Scol, const unsigned char* __restrict__ Tcol,
        const unsigned char* __restrict__ Hcol, const float* __restrict__ Ls,
        float* __restrict__ partials) {
    int n = blockIdx.x >> 4;          // pair (16 row-tiles per pair)
    int t = blockIdx.x & 15;          // row tile
    int tid = threadIdx.x;
    int k = tid >> 7;                 // row r within tile (phase 3)
    int j = tid & (WW - 1);
    int b = n / (CC - 1), c = 1 + (n - b * (CC - 1));
    const float* Lp = Ls + (size_t)(b * CC + c) * HW;

    int i = t * RPB + k;              // this thread's output row (phase 3)
    float lv = Lp[i * WW + j];        // hoisted, coalesced

    __shared__ ulonglong2 colFP[WW], colET[WW], colES[WW];
    __shared__ int sfl[4];

    // preamble: role-split mask build, neighbors direct from L2, ONE barrier.
    size_t cbase = ((size_t)(((b * CC + c) << 7) | j)) << 4;
    if (tid < 128) {                  // waves 0-1: student edge + fp masks
        ulonglong2 S  = *(const ulonglong2*)(Scol + cbase);
        ulonglong2 Sl = ld16z(Scol, cbase - 16, j > 0);
        ulonglong2 Sr = ld16z(Scol, cbase + 16, j < WW - 1);
        ulonglong2 Hc = *(const ulonglong2*)(Hcol + cbase);
        u64 ms0 = S.x, ms1 = S.y;
        // erosion: m & up & down & left & right; shifts insert 0 (border erodes)
        u64 U0 = ms0 << 1, U1 = (ms1 << 1) | (ms0 >> 63);
        u64 D0 = (ms0 >> 1) | (ms1 << 63), D1 = ms1 >> 1;
        u64 er0 = ms0 & U0 & D0 & Sl.x & Sr.x;
        u64 er1 = ms1 & U1 & D1 & Sl.y & Sr.y;
        u64 es0 = ms0 & ~er0, es1 = ms1 & ~er1;
        u64 fp0 = es0 & Hc.x, fp1 = es1 & Hc.y;   // pred = es*logit > 0.5
        colES[j] = make_ulonglong2(es0, es1);
        colFP[j] = make_ulonglong2(fp0, fp1);
        u64 bFgP = __ballot((fp0 | fp1) != 0ull);
        u64 bBgP = __ballot((fp0 & fp1) != ~0ull);
        if ((tid & 63) == 0) sfl[tid >> 6] = (bFgP ? 1 : 0) | (bBgP ? 2 : 0);
    } else if (tid < 256) {           // waves 2-3: teacher edge masks
        ulonglong2 T  = *(const ulonglong2*)(Tcol + cbase);
        ulonglong2 Tl = ld16z(Tcol, cbase - 16, j > 0);
        ulonglong2 Tr = ld16z(Tcol, cbase + 16, j < WW - 1);
        u64 mt0 = T.x, mt1 = T.y;
        u64 Ut0 = mt0 << 1, Ut1 = (mt1 << 1) | (mt0 >> 63);
        u64 Dt0 = (mt0 >> 1) | (mt1 << 63), Dt1 = mt1 >> 1;
        u64 ert0 = mt0 & Ut0 & Dt0 & Tl.x & Tr.x;
        u64 ert1 = mt1 & Ut1 & Dt1 & Tl.y & Tr.y;
        u64 et0 = mt0 & ~ert0, et1 = mt1 & ~ert1;
        colET[j] = make_ulonglong2(et0, et1);
        u64 bFgT = __ballot((et0 | et1) != 0ull);
        u64 bBgT = __ballot((et0 & et1) != ~0ull);
        if ((tid & 63) == 0) sfl[tid >> 6] = (bFgT ? 4 : 0) | (bBgT ? 8 : 0);
    }
    __syncthreads();

    // phase 3: column EDT + expanding-ring row EDT + loss
    ulonglong2 mP = colFP[j];
    ulonglong2 mT = colET[j];
    ulonglong2 eS = colES[j];
    int f = sfl[0] | sfl[1] | sfl[2] | sfl[3];
    bool aP = (f & 3) == 3, aT = (f & 12) == 12;

    int dP  = nbd(mP.x, mP.y, i);
    int dPb = nbd(~mP.x, ~mP.y, i);
    int dT  = nbd(mT.x, mT.y, i);
    int dTb = nbd(~mT.x, ~mT.y, i);

    __shared__ uchar4 sq[RPB][WW];    // d1 per map (255 sentinel; squared on read)
    sq[k][j] = make_uchar4((unsigned char)dP, (unsigned char)dPb,
                           (unsigned char)dT, (unsigned char)dTb);
    __syncthreads();

    int bP = dP * dP, bPb = dPb * dPb, bT = dT * dT, bTb = dTb * dTb;
    int need = 0;
    if (aP) need = max(bP, bPb);
    if (aT) need = max(need, max(bT, bTb));
    // expanding ring: candidates at radius rad are >= rad^2, so once
    // rad^2 >= need (best over maps actually used), the min is final.
    for (int rad = 1; rad < WW; ++rad) {
        int rr = rad * rad;
        if (rr >= need) break;
        if (j >= rad) {
            uchar4 s = sq[k][j - rad];
            bP  = min(bP,  (int)s.x * s.x + rr); bPb = min(bPb, (int)s.y * s.y + rr);
            bT  = min(bT,  (int)s.z * s.z + rr); bTb = min(bTb, (int)s.w * s.w + rr);
        }
        if (j + rad < WW) {
            uchar4 s = sq[k][j + rad];
            bP  = min(bP,  (int)s.x * s.x + rr); bPb = min(bPb, (int)s.y * s.y + rr);
            bT  = min(bT,  (int)s.z * s.z + rr); bTb = min(bTb, (int)s.w * s.w + rr);
        }
        need = 0;
        if (aP) need = max(bP, bPb);
        if (aT) need = max(need, max(bT, bTb));
    }

    float fieldP = aP ? (float)(bP + bPb) : 0.0f;
    float fieldT = aT ? (float)(bT + bTb) : 0.0f;

    bool es = ((i < 64 ? (eS.x >> i) : (eS.y >> (i - 64))) & 1ull) != 0;
    bool et = ((i < 64 ? (mT.x >> i) : (mT.y >> (i - 64))) & 1ull) != 0;
    float predv = es ? lv : 0.0f;
    float targv = et ? (float)c : 0.0f;
    float diff = predv - targv;
    float v = diff * diff * (fieldP + fieldT);

    for (int o = 32; o > 0; o >>= 1) v += __shfl_down(v, o);
    __shared__ float wsum[16];
    int lane = tid & 63, w = tid >> 6;
    if (lane == 0) wsum[w] = v;
    __syncthreads();
    if (tid == 0) {
        float tot = 0.0f;
#pragma unroll
        for (int q = 0; q < 16; ++q) tot += wsum[q];
        partials[blockIdx.x] = tot;   // private slot: no atomic, no fence
    }
}

// final reduction: 416 partials -> 26 pair losses -> scalar. One 64-thread
// block; kernel boundary guarantees k_C's stores are visible.
__global__ void k_fin(const float* __restrict__ partials, float* __restrict__ out) {
    int tid = threadIdx.x;            // 0..63
    float vv = 0.0f;
    if (tid < NPAIR) {
        float s = 0.0f;
#pragma unroll
        for (int t = 0; t < 16; ++t) s += partials[tid * 16 + t];
        vv = logf(s * (1.0f / (float)HW) + 1.0f);
    }
    for (int o = 32; o > 0; o >>= 1) vv += __shfl_down(vv, o);
    if (tid == 0) out[0] = 0.5f * vv; // (1 - LOSS_WEIGHT) * sum
}

extern "C" void kernel_launch(void* const* d_in, const int* in_sizes, int n_in,
                              void* d_out, int out_size, void* d_ws, size_t ws_size,
                              hipStream_t stream) {
    const float* Ls = (const float*)d_in[0];
    const float* Lt = (const float*)d_in[1];
    float* out = (float*)d_out;

    char* w = (char*)d_ws;
    unsigned char* Sc   = (unsigned char*)(w);
    unsigned char* Tc   = (unsigned char*)(w + 57344);
    unsigned char* Hc   = (unsigned char*)(w + 114688);
    float*         part = (float*)        (w + 172032);

    k_pack<<<128, 256, 0, stream>>>(Ls, Lt, Sc, Tc, Hc);
    k_C<<<NBLK, 1024, 0, stream>>>(Sc, Tc, Hc, Ls, part);
    k_fin<<<1, 64, 0, stream>>>(part, out);
}